// Round 1
// baseline (16.629 us; speedup 1.0000x reference)
//
#include <hip/hip_runtime.h>

// Quanvolution: 4-qubit circuit per 2x2 patch, simulated fully in registers.
// x: [64,1,256,256] f32, weights: [1,5] f32 (w[2] unused by the circuit),
// out: [64,128,128,4] f32.
//
// Wire/bit convention: state index idx = b0*8 + b1*4 + b2*2 + b3
// (wire 0 = most significant), matching the reference's [N,2,2,2,2] layout.

__global__ __launch_bounds__(256) void quanv_kernel(
    const float* __restrict__ x, const float* __restrict__ w,
    float* __restrict__ out)
{
    int n = blockIdx.x * blockDim.x + threadIdx.x;   // patch id
    int k = n & 127;            // out col
    int j = (n >> 7) & 127;     // out row
    int b = n >> 14;            // batch

    // 2x2 patch: p0=(2j,2k) p1=(2j,2k+1) p2=(2j+1,2k) p3=(2j+1,2k+1)
    const float* xp = x + (((size_t)b * 256 + 2 * j) * 256 + 2 * k);
    float2 r0 = *reinterpret_cast<const float2*>(xp);
    float2 r1 = *reinterpret_cast<const float2*>(xp + 256);
    float px[4] = {r0.x, r0.y, r1.x, r1.y};

    // weight half-angles (uniform across threads -> scalarized by compiler)
    float w0 = w[0], w1 = w[1], w3 = w[3], w4 = w[4];
    float hs0, hc0, hs1, hc1, hs3, hc3, hs4, hc4;
    __sincosf(0.5f * w0, &hs0, &hc0);
    __sincosf(0.5f * w1, &hs1, &hc1);
    __sincosf(0.5f * w3, &hs3, &hc3);
    __sincosf(0.5f * w4, &hs4, &hc4);

    // data encoding: RY(pi*x)|0> = [cos(pi x/2), sin(pi x/2)]
    const float HPI = 1.57079632679489662f;
    float C[4], S[4];
    #pragma unroll
    for (int q = 0; q < 4; ++q) __sincosf(HPI * px[q], &S[q], &C[q]);

    // RX on wires 0,1 while still factored:
    // u[a] = RX(w) v:  u[0] = c*C - i s*S ; u[1] = c*S - i s*C
    float u0r[2] = { hc0 * C[0],  hc0 * S[0] };
    float u0i[2] = { -hs0 * S[0], -hs0 * C[0] };
    float u1r[2] = { hc1 * C[1],  hc1 * S[1] };
    float u1i[2] = { -hs1 * S[1], -hs1 * C[1] };

    // A[b0][b1] = u0[b0]*u1[b1]  (complex, wires 0,1)
    float Ar[2][2], Ai[2][2];
    #pragma unroll
    for (int a = 0; a < 2; ++a)
        #pragma unroll
        for (int c = 0; c < 2; ++c) {
            Ar[a][c] = u0r[a] * u1r[c] - u0i[a] * u1i[c];
            Ai[a][c] = u0r[a] * u1i[c] + u0i[a] * u1r[c];
        }

    // wires 2,3 real tensor, with CNOT(2,3) already applied:
    // R[b2][b3]: R[1][*] swapped
    float Rp[2][2] = { { C[2] * C[3], C[2] * S[3] },
                       { S[2] * S[3], S[2] * C[3] } };

    // CNOT(0,2) then CNOT(0,3): b0=1 branch picks R'[~b2][~b3]
    float sr[16], si[16];
    #pragma unroll
    for (int i = 0; i < 16; ++i) {
        int b0 = (i >> 3) & 1, b1 = (i >> 2) & 1, b2 = (i >> 1) & 1, b3 = i & 1;
        float rv = b0 ? Rp[b2 ^ 1][b3 ^ 1] : Rp[b2][b3];
        sr[i] = Ar[b0][b1] * rv;
        si[i] = Ai[b0][b1] * rv;
    }

    // RY(w3) on wire 0: mixes idx <-> idx+8
    #pragma unroll
    for (int i = 0; i < 8; ++i) {
        float t0r = sr[i], t0i = si[i], t1r = sr[i + 8], t1i = si[i + 8];
        sr[i]     = hc3 * t0r - hs3 * t1r;  si[i]     = hc3 * t0i - hs3 * t1i;
        sr[i + 8] = hs3 * t0r + hc3 * t1r;  si[i + 8] = hs3 * t0i + hc3 * t1i;
    }
    // RY(w4) on wire 3: mixes idx <-> idx+1
    #pragma unroll
    for (int i = 0; i < 16; i += 2) {
        float t0r = sr[i], t0i = si[i], t1r = sr[i + 1], t1i = si[i + 1];
        sr[i]     = hc4 * t0r - hs4 * t1r;  si[i]     = hc4 * t0i - hs4 * t1i;
        sr[i + 1] = hs4 * t0r + hc4 * t1r;  si[i + 1] = hs4 * t0i + hc4 * t1i;
    }

    // probabilities and <Z_j>
    float z0 = 0.f, z1 = 0.f, z2 = 0.f, z3 = 0.f;
    #pragma unroll
    for (int i = 0; i < 16; ++i) {
        float p = sr[i] * sr[i] + si[i] * si[i];
        z0 += (i & 8) ? -p : p;
        z1 += (i & 4) ? -p : p;
        z2 += (i & 2) ? -p : p;
        z3 += (i & 1) ? -p : p;
    }

    float4 o = make_float4(z0, z1, z2, z3);
    *reinterpret_cast<float4*>(out + (size_t)n * 4) = o;
}

extern "C" void kernel_launch(void* const* d_in, const int* in_sizes, int n_in,
                              void* d_out, int out_size, void* d_ws, size_t ws_size,
                              hipStream_t stream) {
    const float* x = (const float*)d_in[0];
    const float* w = (const float*)d_in[1];
    float* out = (float*)d_out;
    const int total = 64 * 128 * 128;   // patches
    quanv_kernel<<<total / 256, 256, 0, stream>>>(x, w, out);
}

// Round 2
// 10.748 us; speedup vs baseline: 1.5472x; 1.5472x over previous
//
#include <hip/hip_runtime.h>

// Quanvolution — closed-form. The 4-qubit circuit's Z-expectations reduce to:
//   z0 = cos(w0)cos(w3)*cos(pi x0) - sin(w3)*sin(pi x0)*sin(pi x2)
//   z1 = cos(w1)*cos(pi x1)
//   z2 = cos(w0)*cos(pi x0)*cos(pi x2)
//   z3 = cos(w0)cos(w4)*cos(pi x0)cos(pi x2)cos(pi x3) - sin(w4)*sin(pi x3)
// with patch (x0,x1 / x2,x3) = 2x2 block. x in [0,1) so sin(pi x) is
// v_sin_f32(0.5*x) directly (revolutions, no range reduction needed).
//
// x: [64,1,256,256] f32, weights: [1,5] f32, out: [64,128,128,4] f32.

__global__ __launch_bounds__(256) void quanv_kernel(
    const float* __restrict__ x, const float* __restrict__ w,
    float* __restrict__ out)
{
    int n = blockIdx.x * 256 + threadIdx.x;   // patch id
    int k = n & 127;            // out col
    int j = (n >> 7) & 127;     // out row
    int b = n >> 14;            // batch

    const float* xp = x + (((size_t)b * 256 + 2 * j) * 256 + 2 * k);
    float2 r0 = *reinterpret_cast<const float2*>(xp);        // x0, x1
    float2 r1 = *reinterpret_cast<const float2*>(xp + 256);  // x2, x3

    // uniform weight coefficients (w[2] unused by the circuit)
    float cw0 = cosf(w[0]);
    float cw1 = cosf(w[1]);
    float sw3, cw3; sincosf(w[3], &sw3, &cw3);
    float sw4, cw4; sincosf(w[4], &sw4, &cw4);
    float A = cw0 * cw3;      // z0 cos-term
    float E = cw0 * cw4;      // z3 cos-term

    // data trig: sin/cos(pi*x) via revolutions input 0.5*x in [0, 0.5)
    float c0 = __builtin_amdgcn_cosf(0.5f * r0.x);
    float s0 = __builtin_amdgcn_sinf(0.5f * r0.x);
    float c1 = __builtin_amdgcn_cosf(0.5f * r0.y);
    float c2 = __builtin_amdgcn_cosf(0.5f * r1.x);
    float s2 = __builtin_amdgcn_sinf(0.5f * r1.x);
    float c3 = __builtin_amdgcn_cosf(0.5f * r1.y);
    float s3 = __builtin_amdgcn_sinf(0.5f * r1.y);

    float z0 = A * c0 - sw3 * s0 * s2;
    float z1 = cw1 * c1;
    float c0c2 = c0 * c2;
    float z2 = cw0 * c0c2;
    float z3 = E * c0c2 * c3 - sw4 * s3;

    *reinterpret_cast<float4*>(out + (size_t)n * 4) = make_float4(z0, z1, z2, z3);
}

extern "C" void kernel_launch(void* const* d_in, const int* in_sizes, int n_in,
                              void* d_out, int out_size, void* d_ws, size_t ws_size,
                              hipStream_t stream) {
    const float* x = (const float*)d_in[0];
    const float* w = (const float*)d_in[1];
    float* out = (float*)d_out;
    const int total = 64 * 128 * 128;   // patches
    quanv_kernel<<<total / 256, 256, 0, stream>>>(x, w, out);
}

// Round 4
// 10.265 us; speedup vs baseline: 1.6200x; 1.0471x over previous
//
#include <hip/hip_runtime.h>

// Quanvolution — closed-form, 2 patches per thread.
//   z0 = cos(w0)cos(w3)*c0 - sin(w3)*s0*s2
//   z1 = cos(w1)*c1
//   z2 = cos(w0)*c0*c2
//   z3 = cos(w0)cos(w4)*c0*c2*c3 - sin(w4)*s3
// where ci=cos(pi xi), si=sin(pi xi) over the 2x2 patch (x0,x1 / x2,x3).
// x in [0,1) -> trig in revolutions: v_sin/v_cos(0.5*x), no range reduction.
//
// x: [64,1,256,256] f32, weights: [1,5] f32, out: [64,128,128,4] f32.
// Thread t handles patches 2t and 2t+1 (always same image row):
// two float4 row loads (16B/lane), two 16B nontemporal stores (32B contiguous).

typedef float f32x4 __attribute__((ext_vector_type(4)));

__global__ __launch_bounds__(256) void quanv_kernel(
    const float* __restrict__ x, const float* __restrict__ w,
    float* __restrict__ out)
{
    int t = blockIdx.x * 256 + threadIdx.x;       // 0 .. 524287
    int kk = (t & 63) * 2;          // first patch col (0..126 even)
    int j  = (t >> 6) & 127;        // patch row
    int b  = t >> 13;               // batch

    const float* xp = x + (((size_t)b * 256 + 2 * j) * 256 + 2 * kk);
    f32x4 r0 = *reinterpret_cast<const f32x4*>(xp);        // row 2j  : xA0 xA1 xB0 xB1
    f32x4 r1 = *reinterpret_cast<const f32x4*>(xp + 256);  // row 2j+1: xA2 xA3 xB2 xB3

    // uniform weight coefficients (w[2] unused by the circuit)
    float cw0 = cosf(w[0]);
    float cw1 = cosf(w[1]);
    float sw3, cw3; sincosf(w[3], &sw3, &cw3);
    float sw4, cw4; sincosf(w[4], &sw4, &cw4);
    float A = cw0 * cw3;
    float E = cw0 * cw4;

    f32x4 oA, oB;
    {   // patch A: x0=r0.x x1=r0.y x2=r1.x x3=r1.y
        float c0 = __builtin_amdgcn_cosf(0.5f * r0.x);
        float s0 = __builtin_amdgcn_sinf(0.5f * r0.x);
        float c1 = __builtin_amdgcn_cosf(0.5f * r0.y);
        float c2 = __builtin_amdgcn_cosf(0.5f * r1.x);
        float s2 = __builtin_amdgcn_sinf(0.5f * r1.x);
        float c3 = __builtin_amdgcn_cosf(0.5f * r1.y);
        float s3 = __builtin_amdgcn_sinf(0.5f * r1.y);
        float c0c2 = c0 * c2;
        oA = (f32x4){ A * c0 - sw3 * s0 * s2,
                      cw1 * c1,
                      cw0 * c0c2,
                      E * c0c2 * c3 - sw4 * s3 };
    }
    {   // patch B: x0=r0.z x1=r0.w x2=r1.z x3=r1.w
        float c0 = __builtin_amdgcn_cosf(0.5f * r0.z);
        float s0 = __builtin_amdgcn_sinf(0.5f * r0.z);
        float c1 = __builtin_amdgcn_cosf(0.5f * r0.w);
        float c2 = __builtin_amdgcn_cosf(0.5f * r1.z);
        float s2 = __builtin_amdgcn_sinf(0.5f * r1.z);
        float c3 = __builtin_amdgcn_cosf(0.5f * r1.w);
        float s3 = __builtin_amdgcn_sinf(0.5f * r1.w);
        float c0c2 = c0 * c2;
        oB = (f32x4){ A * c0 - sw3 * s0 * s2,
                      cw1 * c1,
                      cw0 * c0c2,
                      E * c0c2 * c3 - sw4 * s3 };
    }

    f32x4* op = reinterpret_cast<f32x4*>(out + (size_t)t * 8);
    __builtin_nontemporal_store(oA, op);
    __builtin_nontemporal_store(oB, op + 1);
}

extern "C" void kernel_launch(void* const* d_in, const int* in_sizes, int n_in,
                              void* d_out, int out_size, void* d_ws, size_t ws_size,
                              hipStream_t stream) {
    const float* x = (const float*)d_in[0];
    const float* w = (const float*)d_in[1];
    float* out = (float*)d_out;
    const int threads = 64 * 128 * 64;   // 2 patches per thread
    quanv_kernel<<<threads / 256, 256, 0, stream>>>(x, w, out);
}